// Round 1
// baseline (219.760 us; speedup 1.0000x reference)
//
#include <hip/hip_runtime.h>

#define S_LEN 2048
#define NHEAD 16

using f32x4  = __attribute__((ext_vector_type(4))) float;
using bf16x8 = __attribute__((ext_vector_type(8))) __bf16;

__device__ __forceinline__ unsigned short f2bf(float f) {
  union { float f; unsigned u; } v; v.f = f;
  unsigned r = v.u + 0x7FFFu + ((v.u >> 16) & 1u);
  return (unsigned short)(r >> 16);
}
__device__ __forceinline__ float bf2f(unsigned short h) {
  union { unsigned u; float f; } v; v.u = ((unsigned)h) << 16; return v.f;
}
__device__ __forceinline__ void unpack8(uint4 u, float x[8]) {
  x[0]=bf2f((unsigned short)(u.x&0xffff)); x[1]=bf2f((unsigned short)(u.x>>16));
  x[2]=bf2f((unsigned short)(u.y&0xffff)); x[3]=bf2f((unsigned short)(u.y>>16));
  x[4]=bf2f((unsigned short)(u.z&0xffff)); x[5]=bf2f((unsigned short)(u.z>>16));
  x[6]=bf2f((unsigned short)(u.w&0xffff)); x[7]=bf2f((unsigned short)(u.w>>16));
}
__device__ __forceinline__ uint4 pack8(const unsigned short o[8]) {
  uint4 u;
  u.x = (unsigned)o[0] | ((unsigned)o[1]<<16);
  u.y = (unsigned)o[2] | ((unsigned)o[3]<<16);
  u.z = (unsigned)o[4] | ((unsigned)o[5]<<16);
  u.w = (unsigned)o[6] | ((unsigned)o[7]<<16);
  return u;
}
__device__ __forceinline__ void gload16(const void* g, void* l) {
  __builtin_amdgcn_global_load_lds(
      (const __attribute__((address_space(1))) unsigned int*)g,
      (__attribute__((address_space(3))) unsigned int*)l, 16, 0, 0);
}
__device__ __forceinline__ void store_c(float* C, size_t off, float v) { C[off] = v; }
__device__ __forceinline__ void store_c(unsigned short* C, size_t off, float v) { C[off] = f2bf(v); }

// ---------------- fp32 -> bf16 convert (vectorized, 8 elems/thread) ----------------
__global__ __launch_bounds__(256) void k_cvt(const float* __restrict__ in,
                                             unsigned short* __restrict__ out, int n8) {
  int i = blockIdx.x * 256 + threadIdx.x;
  if (i >= n8) return;
  const float4* p = (const float4*)in + 2 * (size_t)i;
  float4 a = p[0], b = p[1];
  unsigned short o[8] = { f2bf(a.x), f2bf(a.y), f2bf(a.z), f2bf(a.w),
                          f2bf(b.x), f2bf(b.y), f2bf(b.z), f2bf(b.w) };
  ((uint4*)out)[i] = pack8(o);
}

// ---------------- fp32 [R][C] -> bf16 transposed [C][R] ----------------
__global__ __launch_bounds__(256) void k_transpose_cvt(const float* __restrict__ in,
                                                       unsigned short* __restrict__ out,
                                                       int R, int C) {
  __shared__ float T[64][65];
  int r0 = blockIdx.x * 64, c0 = blockIdx.y * 64;
  int tid = threadIdx.x;
#pragma unroll
  for (int i = 0; i < 16; ++i) {
    int idx = tid + i * 256;
    int r = idx >> 6, c = idx & 63;
    T[r][c] = in[(size_t)(r0 + r) * C + c0 + c];
  }
  __syncthreads();
#pragma unroll
  for (int i = 0; i < 8; ++i) {
    int idx = tid + i * 256;
    int co = idx >> 5, rp = (idx & 31) * 2;
    unsigned v = (unsigned)f2bf(T[rp][co]) | ((unsigned)f2bf(T[rp + 1][co]) << 16);
    *(unsigned*)&out[(size_t)(c0 + co) * R + r0 + rp] = v;
  }
}

// ---------------- bf16 GEMM: C[M][N] = A[M][K] * Bt[N][K]^T  (m97-style 128x128x32) --
template <typename OUT_T>
__global__ __launch_bounds__(256) void k_gemm_bt(const unsigned short* __restrict__ A,
                                                 const unsigned short* __restrict__ Bt,
                                                 OUT_T* __restrict__ C,
                                                 int M, int N, int K) {
  __shared__ unsigned short As[128 * 32];
  __shared__ unsigned short Bs[128 * 32];
  int m0 = blockIdx.x * 128, n0 = blockIdx.y * 128;
  int tid = threadIdx.x;
  int lane = tid & 63, w = tid >> 6;
  int wr = w >> 1, wc = w & 1;
  int li = lane & 15, g = lane >> 4;

  // staging: flat chunk f covers bf16 elems [f*8, f*8+8) of the linear [128][32] tile
  const unsigned short* a_s0 = A + (size_t)(m0 + (tid >> 2)) * K + (tid & 3) * 8;
  const unsigned short* a_s1 = A + (size_t)(m0 + 64 + (tid >> 2)) * K + (tid & 3) * 8;
  const unsigned short* b_s0 = Bt + (size_t)(n0 + (tid >> 2)) * K + (tid & 3) * 8;
  const unsigned short* b_s1 = Bt + (size_t)(n0 + 64 + (tid >> 2)) * K + (tid & 3) * 8;
  unsigned short* As_d0 = &As[(w * 64) * 8];
  unsigned short* As_d1 = &As[(256 + w * 64) * 8];
  unsigned short* Bs_d0 = &Bs[(w * 64) * 8];
  unsigned short* Bs_d1 = &Bs[(256 + w * 64) * 8];

  f32x4 acc[4][4];
#pragma unroll
  for (int i = 0; i < 4; ++i)
#pragma unroll
    for (int j = 0; j < 4; ++j) acc[i][j] = (f32x4){0.f, 0.f, 0.f, 0.f};

  int nk = K >> 5;
  for (int kt = 0; kt < nk; ++kt) {
    int k0 = kt << 5;
    gload16(a_s0 + k0, As_d0);
    gload16(a_s1 + k0, As_d1);
    gload16(b_s0 + k0, Bs_d0);
    gload16(b_s1 + k0, Bs_d1);
    __syncthreads();
    bf16x8 af[4], bfr[4];
#pragma unroll
    for (int i = 0; i < 4; ++i)
      af[i] = *(const bf16x8*)&As[(wr * 64 + i * 16 + li) * 32 + g * 8];
#pragma unroll
    for (int j = 0; j < 4; ++j)
      bfr[j] = *(const bf16x8*)&Bs[(wc * 64 + j * 16 + li) * 32 + g * 8];
#pragma unroll
    for (int i = 0; i < 4; ++i)
#pragma unroll
      for (int j = 0; j < 4; ++j)
        acc[i][j] = __builtin_amdgcn_mfma_f32_16x16x32_bf16(af[i], bfr[j], acc[i][j], 0, 0, 0);
    __syncthreads();
  }
#pragma unroll
  for (int i = 0; i < 4; ++i) {
    int row = m0 + wr * 64 + i * 16 + g * 4;
#pragma unroll
    for (int j = 0; j < 4; ++j) {
      int col = n0 + wc * 64 + j * 16 + li;
#pragma unroll
      for (int r = 0; r < 4; ++r) store_c(C, (size_t)(row + r) * N + col, acc[i][j][r]);
    }
  }
}

// ---------------- rope + head split:  qkv[B*S][3072] -> Qh,Kh [BH][S][64], Vt [BH][64][S]
__global__ __launch_bounds__(256) void k_rope_split(const unsigned short* __restrict__ qkv,
                                                    unsigned short* __restrict__ Qh,
                                                    unsigned short* __restrict__ Kh,
                                                    unsigned short* __restrict__ Vt) {
  int blk = blockIdx.x;                 // b*512 + h*32 + st
  int st = blk & 31, h = (blk >> 5) & 15, b = blk >> 9;
  int s0 = st * 64;
  int tid = threadIdx.x;
  int sl = tid >> 2, quad = tid & 3;
  int s = s0 + sl;
  int bh = b * NHEAD + h;

  float cs[8], sn[8];
#pragma unroll
  for (int j = 0; j < 8; ++j) {
    int pr = quad * 8 + j;
    float freq = 1.0f / (powf(10000.0f, (float)pr * (1.0f / 32.0f)) + 1.1920928955078125e-07f);
    float ang = (float)s * freq;
    sincosf(ang, &sn[j], &cs[j]);
  }
  const unsigned short* row = qkv + (size_t)(b * S_LEN + s) * 3072;
  // Q (pre-scaled by DIM_K^-0.5 = 1/32, exact in bf16)
  {
    float x1[8], x2[8];
    unpack8(*(const uint4*)&row[h * 64 + quad * 8], x1);
    unpack8(*(const uint4*)&row[h * 64 + 32 + quad * 8], x2);
    unsigned short o1[8], o2[8];
#pragma unroll
    for (int j = 0; j < 8; ++j) {
      o1[j] = f2bf((x1[j] * cs[j] - x2[j] * sn[j]) * 0.03125f);
      o2[j] = f2bf((x2[j] * cs[j] + x1[j] * sn[j]) * 0.03125f);
    }
    unsigned short* qp = Qh + ((size_t)bh * S_LEN + s) * 64 + quad * 8;
    *(uint4*)qp = pack8(o1);
    *(uint4*)(qp + 32) = pack8(o2);
  }
  // K (no scale)
  {
    float x1[8], x2[8];
    unpack8(*(const uint4*)&row[1024 + h * 64 + quad * 8], x1);
    unpack8(*(const uint4*)&row[1024 + h * 64 + 32 + quad * 8], x2);
    unsigned short o1[8], o2[8];
#pragma unroll
    for (int j = 0; j < 8; ++j) {
      o1[j] = f2bf(x1[j] * cs[j] - x2[j] * sn[j]);
      o2[j] = f2bf(x2[j] * cs[j] + x1[j] * sn[j]);
    }
    unsigned short* kp = Kh + ((size_t)bh * S_LEN + s) * 64 + quad * 8;
    *(uint4*)kp = pack8(o1);
    *(uint4*)(kp + 32) = pack8(o2);
  }
  // V: transpose 64x64 tile through LDS -> Vt[bh][d][s]
  __shared__ unsigned short Vl[64 * 72];
#pragma unroll
  for (int i = 0; i < 2; ++i) {
    int c = tid + i * 256;
    int r = c >> 3, c8 = (c & 7) * 8;
    *(uint4*)&Vl[r * 72 + c8] =
        *(const uint4*)&qkv[(size_t)(b * S_LEN + s0 + r) * 3072 + 2048 + h * 64 + c8];
  }
  __syncthreads();
  int d = tid >> 2, sc4 = tid & 3;
  unsigned o[8];
#pragma unroll
  for (int jj = 0; jj < 8; ++jj) {
    int sidx = sc4 * 16 + jj * 2;
    o[jj] = (unsigned)Vl[sidx * 72 + d] | ((unsigned)Vl[(sidx + 1) * 72 + d] << 16);
  }
  unsigned short* vp = Vt + ((size_t)bh * 64 + d) * S_LEN + s0 + sc4 * 16;
  *(uint4*)vp = make_uint4(o[0], o[1], o[2], o[3]);
  *(uint4*)(vp + 8) = make_uint4(o[4], o[5], o[6], o[7]);
}

// ---------------- causal flash attention ----------------
// grid (32 qtiles, 32 bh); 4 waves; wave w owns q rows [w*16, w*16+16)
__global__ __launch_bounds__(256) void k_attn(const unsigned short* __restrict__ Qh,
                                              const unsigned short* __restrict__ Kh,
                                              const unsigned short* __restrict__ Vt,
                                              unsigned short* __restrict__ O) {
  int qt = blockIdx.x, bh = blockIdx.y;
  int b = bh >> 4, h = bh & 15;
  int q0 = qt * 64;
  __shared__ unsigned short Qs[64 * 72];
  __shared__ unsigned short Ks[64 * 72];
  __shared__ unsigned short Vs[64 * 72];
  __shared__ unsigned short Ps[64 * 72];
  int tid = threadIdx.x, lane = tid & 63, w = tid >> 6;
  int li = lane & 15, g = lane >> 4;
  const unsigned short* Qg = Qh + ((size_t)bh * S_LEN + q0) * 64;
  const unsigned short* Kg = Kh + (size_t)bh * S_LEN * 64;
  const unsigned short* Vg = Vt + (size_t)bh * 64 * S_LEN;

#pragma unroll
  for (int i = 0; i < 2; ++i) {
    int c = tid + i * 256;
    int r = c >> 3, c8 = (c & 7) * 8;
    *(uint4*)&Qs[r * 72 + c8] = *(const uint4*)&Qg[r * 64 + c8];
  }
  __syncthreads();
  bf16x8 aq0 = *(const bf16x8*)&Qs[(w * 16 + li) * 72 + g * 8];
  bf16x8 aq1 = *(const bf16x8*)&Qs[(w * 16 + li) * 72 + 32 + g * 8];

  f32x4 acc_o[4];
  float m_run[4], l_run[4];
#pragma unroll
  for (int r = 0; r < 4; ++r) { m_run[r] = -1e30f; l_run[r] = 0.f; }
#pragma unroll
  for (int j = 0; j < 4; ++j) acc_o[j] = (f32x4){0.f, 0.f, 0.f, 0.f};

  int nt = qt + 1;
  for (int t = 0; t < nt; ++t) {
    int kv0 = t * 64;
    __syncthreads();  // prior-iter LDS reads complete
#pragma unroll
    for (int i = 0; i < 2; ++i) {
      int c = tid + i * 256;
      int r = c >> 3, c8 = (c & 7) * 8;
      *(uint4*)&Ks[r * 72 + c8] = *(const uint4*)&Kg[(size_t)(kv0 + r) * 64 + c8];
      *(uint4*)&Vs[r * 72 + c8] = *(const uint4*)&Vg[(size_t)r * S_LEN + kv0 + c8];
    }
    __syncthreads();

    f32x4 sc[4];
#pragma unroll
    for (int j = 0; j < 4; ++j) {
      bf16x8 b0 = *(const bf16x8*)&Ks[(j * 16 + li) * 72 + g * 8];
      bf16x8 b1 = *(const bf16x8*)&Ks[(j * 16 + li) * 72 + 32 + g * 8];
      f32x4 z = (f32x4){0.f, 0.f, 0.f, 0.f};
      z = __builtin_amdgcn_mfma_f32_16x16x32_bf16(aq0, b0, z, 0, 0, 0);
      z = __builtin_amdgcn_mfma_f32_16x16x32_bf16(aq1, b1, z, 0, 0, 0);
      sc[j] = z;
    }
    if (t == nt - 1) {  // diagonal tile (kv0 == q0): mask col > row
#pragma unroll
      for (int j = 0; j < 4; ++j)
#pragma unroll
        for (int r = 0; r < 4; ++r)
          if (j * 16 + li > w * 16 + g * 4 + r) sc[j][r] = -1e30f;
    }
    float fac[4];
#pragma unroll
    for (int r = 0; r < 4; ++r) {
      float m_ = fmaxf(fmaxf(sc[0][r], sc[1][r]), fmaxf(sc[2][r], sc[3][r]));
      m_ = fmaxf(m_, __shfl_xor(m_, 1));
      m_ = fmaxf(m_, __shfl_xor(m_, 2));
      m_ = fmaxf(m_, __shfl_xor(m_, 4));
      m_ = fmaxf(m_, __shfl_xor(m_, 8));
      float mn = fmaxf(m_run[r], m_);
      fac[r] = __expf(m_run[r] - mn);
      m_run[r] = mn;
      float s_ = 0.f;
#pragma unroll
      for (int j = 0; j < 4; ++j) {
        float p = __expf(sc[j][r] - mn);
        sc[j][r] = p;
        s_ += p;
      }
      s_ += __shfl_xor(s_, 1);
      s_ += __shfl_xor(s_, 2);
      s_ += __shfl_xor(s_, 4);
      s_ += __shfl_xor(s_, 8);
      l_run[r] = l_run[r] * fac[r] + s_;
    }
#pragma unroll
    for (int j = 0; j < 4; ++j)
#pragma unroll
      for (int r = 0; r < 4; ++r) acc_o[j][r] *= fac[r];
    // stage P (per-wave private rows; same-wave write->read, no barrier needed)
#pragma unroll
    for (int j = 0; j < 4; ++j)
#pragma unroll
      for (int r = 0; r < 4; ++r)
        Ps[(w * 16 + g * 4 + r) * 72 + j * 16 + li] = f2bf(sc[j][r]);
    bf16x8 pa0 = *(const bf16x8*)&Ps[(w * 16 + li) * 72 + g * 8];
    bf16x8 pa1 = *(const bf16x8*)&Ps[(w * 16 + li) * 72 + 32 + g * 8];
#pragma unroll
    for (int jd = 0; jd < 4; ++jd) {
      bf16x8 v0 = *(const bf16x8*)&Vs[(jd * 16 + li) * 72 + g * 8];
      bf16x8 v1 = *(const bf16x8*)&Vs[(jd * 16 + li) * 72 + 32 + g * 8];
      acc_o[jd] = __builtin_amdgcn_mfma_f32_16x16x32_bf16(pa0, v0, acc_o[jd], 0, 0, 0);
      acc_o[jd] = __builtin_amdgcn_mfma_f32_16x16x32_bf16(pa1, v1, acc_o[jd], 0, 0, 0);
    }
  }
#pragma unroll
  for (int r = 0; r < 4; ++r) {
    float inv = 1.0f / l_run[r];
    int qrow = q0 + w * 16 + g * 4 + r;
    unsigned short* op = O + ((size_t)(b * S_LEN + qrow)) * 1024 + h * 64;
#pragma unroll
    for (int jd = 0; jd < 4; ++jd) op[jd * 16 + li] = f2bf(acc_o[jd][r] * inv);
  }
}

extern "C" void kernel_launch(void* const* d_in, const int* in_sizes, int n_in,
                              void* d_out, int out_size, void* d_ws, size_t ws_size,
                              hipStream_t stream) {
  const float* x = (const float*)d_in[0];
  const float* Wqkv = (const float*)d_in[1];
  const float* Wout = (const float*)d_in[2];
  float* out = (float*)d_out;
  char* ws = (char*)d_ws;
  // layout (bytes): xb/O 0..8M | WqkvT 8..14M | WoutT 14..16M | qkv 16..40M |
  //                 Qh 40..48M | Kh 48..56M | Vt 56..64M
  unsigned short* xb = (unsigned short*)(ws);
  unsigned short* WqkvT = (unsigned short*)(ws + ((size_t)8 << 20));
  unsigned short* WoutT = (unsigned short*)(ws + ((size_t)14 << 20));
  unsigned short* qkv = (unsigned short*)(ws + ((size_t)16 << 20));
  unsigned short* Qh = (unsigned short*)(ws + ((size_t)40 << 20));
  unsigned short* Kh = (unsigned short*)(ws + ((size_t)48 << 20));
  unsigned short* Vt = (unsigned short*)(ws + ((size_t)56 << 20));

  k_cvt<<<2048, 256, 0, stream>>>(x, xb, 4096 * 1024 / 8);
  k_transpose_cvt<<<dim3(16, 48), 256, 0, stream>>>(Wqkv, WqkvT, 1024, 3072);
  k_transpose_cvt<<<dim3(16, 16), 256, 0, stream>>>(Wout, WoutT, 1024, 1024);
  k_gemm_bt<unsigned short><<<dim3(32, 24), 256, 0, stream>>>(xb, WqkvT, qkv, 4096, 3072, 1024);
  k_rope_split<<<1024, 256, 0, stream>>>(qkv, Qh, Kh, Vt);
  k_attn<<<dim3(32, 32), 256, 0, stream>>>(Qh, Kh, Vt, xb /* reuse as O [B][S][1024] */);
  k_gemm_bt<float><<<dim3(32, 8), 256, 0, stream>>>(xb, WoutT, out, 4096, 1024, 1024);
}

// Round 3
// 165.118 us; speedup vs baseline: 1.3309x; 1.3309x over previous
//
#include <hip/hip_runtime.h>

#define S_LEN 2048
#define NHEAD 16

using f32x4  = __attribute__((ext_vector_type(4))) float;
using f32x16 = __attribute__((ext_vector_type(16))) float;
using bf16x8 = __attribute__((ext_vector_type(8))) __bf16;

__device__ __forceinline__ unsigned short f2bf(float f) {
  union { float f; unsigned u; } v; v.f = f;
  unsigned r = v.u + 0x7FFFu + ((v.u >> 16) & 1u);
  return (unsigned short)(r >> 16);
}
__device__ __forceinline__ float bf2f(unsigned short h) {
  union { unsigned u; float f; } v; v.u = ((unsigned)h) << 16; return v.f;
}
__device__ __forceinline__ void unpack8(uint4 u, float x[8]) {
  x[0]=bf2f((unsigned short)(u.x&0xffff)); x[1]=bf2f((unsigned short)(u.x>>16));
  x[2]=bf2f((unsigned short)(u.y&0xffff)); x[3]=bf2f((unsigned short)(u.y>>16));
  x[4]=bf2f((unsigned short)(u.z&0xffff)); x[5]=bf2f((unsigned short)(u.z>>16));
  x[6]=bf2f((unsigned short)(u.w&0xffff)); x[7]=bf2f((unsigned short)(u.w>>16));
}
__device__ __forceinline__ uint4 pack8(const unsigned short o[8]) {
  uint4 u;
  u.x = (unsigned)o[0] | ((unsigned)o[1]<<16);
  u.y = (unsigned)o[2] | ((unsigned)o[3]<<16);
  u.z = (unsigned)o[4] | ((unsigned)o[5]<<16);
  u.w = (unsigned)o[6] | ((unsigned)o[7]<<16);
  return u;
}
__device__ __forceinline__ void gload16(const void* g, void* l) {
  __builtin_amdgcn_global_load_lds(
      (const __attribute__((address_space(1))) unsigned int*)g,
      (__attribute__((address_space(3))) unsigned int*)l, 16, 0, 0);
}
__device__ __forceinline__ void store_c(float* C, size_t off, float v) { C[off] = v; }
__device__ __forceinline__ void store_c(unsigned short* C, size_t off, float v) { C[off] = f2bf(v); }

// ---------------- fp32 -> bf16 convert (vectorized, 8 elems/thread) ----------------
__global__ __launch_bounds__(256) void k_cvt(const float* __restrict__ in,
                                             unsigned short* __restrict__ out, int n8) {
  int i = blockIdx.x * 256 + threadIdx.x;
  if (i >= n8) return;
  const float4* p = (const float4*)in + 2 * (size_t)i;
  float4 a = p[0], b = p[1];
  unsigned short o[8] = { f2bf(a.x), f2bf(a.y), f2bf(a.z), f2bf(a.w),
                          f2bf(b.x), f2bf(b.y), f2bf(b.z), f2bf(b.w) };
  ((uint4*)out)[i] = pack8(o);
}

// ---------------- fp32 [R][C] -> bf16 transposed [C][R] ----------------
__global__ __launch_bounds__(256) void k_transpose_cvt(const float* __restrict__ in,
                                                       unsigned short* __restrict__ out,
                                                       int R, int C) {
  __shared__ float T[64][65];
  int r0 = blockIdx.x * 64, c0 = blockIdx.y * 64;
  int tid = threadIdx.x;
#pragma unroll
  for (int i = 0; i < 16; ++i) {
    int idx = tid + i * 256;
    int r = idx >> 6, c = idx & 63;
    T[r][c] = in[(size_t)(r0 + r) * C + c0 + c];
  }
  __syncthreads();
#pragma unroll
  for (int i = 0; i < 8; ++i) {
    int idx = tid + i * 256;
    int co = idx >> 5, rp = (idx & 31) * 2;
    unsigned v = (unsigned)f2bf(T[rp][co]) | ((unsigned)f2bf(T[rp + 1][co]) << 16);
    *(unsigned*)&out[(size_t)(c0 + co) * R + r0 + rp] = v;
  }
}

// ---------------- bf16 GEMM: C[M][N] = A[M][K] * Bt[N][K]^T  (m97-style 128x128x32) --
template <typename OUT_T>
__global__ __launch_bounds__(256) void k_gemm_bt(const unsigned short* __restrict__ A,
                                                 const unsigned short* __restrict__ Bt,
                                                 OUT_T* __restrict__ C,
                                                 int M, int N, int K) {
  __shared__ unsigned short As[128 * 32];
  __shared__ unsigned short Bs[128 * 32];
  int m0 = blockIdx.x * 128, n0 = blockIdx.y * 128;
  int tid = threadIdx.x;
  int lane = tid & 63, w = tid >> 6;
  int wr = w >> 1, wc = w & 1;
  int li = lane & 15, g = lane >> 4;

  const unsigned short* a_s0 = A + (size_t)(m0 + (tid >> 2)) * K + (tid & 3) * 8;
  const unsigned short* a_s1 = A + (size_t)(m0 + 64 + (tid >> 2)) * K + (tid & 3) * 8;
  const unsigned short* b_s0 = Bt + (size_t)(n0 + (tid >> 2)) * K + (tid & 3) * 8;
  const unsigned short* b_s1 = Bt + (size_t)(n0 + 64 + (tid >> 2)) * K + (tid & 3) * 8;
  unsigned short* As_d0 = &As[(w * 64) * 8];
  unsigned short* As_d1 = &As[(256 + w * 64) * 8];
  unsigned short* Bs_d0 = &Bs[(w * 64) * 8];
  unsigned short* Bs_d1 = &Bs[(256 + w * 64) * 8];

  f32x4 acc[4][4];
#pragma unroll
  for (int i = 0; i < 4; ++i)
#pragma unroll
    for (int j = 0; j < 4; ++j) acc[i][j] = (f32x4){0.f, 0.f, 0.f, 0.f};

  int nk = K >> 5;
  for (int kt = 0; kt < nk; ++kt) {
    int k0 = kt << 5;
    gload16(a_s0 + k0, As_d0);
    gload16(a_s1 + k0, As_d1);
    gload16(b_s0 + k0, Bs_d0);
    gload16(b_s1 + k0, Bs_d1);
    __syncthreads();
    bf16x8 af[4], bfr[4];
#pragma unroll
    for (int i = 0; i < 4; ++i)
      af[i] = *(const bf16x8*)&As[(wr * 64 + i * 16 + li) * 32 + g * 8];
#pragma unroll
    for (int j = 0; j < 4; ++j)
      bfr[j] = *(const bf16x8*)&Bs[(wc * 64 + j * 16 + li) * 32 + g * 8];
#pragma unroll
    for (int i = 0; i < 4; ++i)
#pragma unroll
      for (int j = 0; j < 4; ++j)
        acc[i][j] = __builtin_amdgcn_mfma_f32_16x16x32_bf16(af[i], bfr[j], acc[i][j], 0, 0, 0);
    __syncthreads();
  }
#pragma unroll
  for (int i = 0; i < 4; ++i) {
    int row = m0 + wr * 64 + i * 16 + g * 4;
#pragma unroll
    for (int j = 0; j < 4; ++j) {
      int col = n0 + wc * 64 + j * 16 + li;
#pragma unroll
      for (int r = 0; r < 4; ++r) store_c(C, (size_t)(row + r) * N + col, acc[i][j][r]);
    }
  }
}

// ---------------- rope + head split:  qkv[B*S][3072] -> Qh,Kh [BH][S][64], Vt [BH][64][S]
__global__ __launch_bounds__(256) void k_rope_split(const unsigned short* __restrict__ qkv,
                                                    unsigned short* __restrict__ Qh,
                                                    unsigned short* __restrict__ Kh,
                                                    unsigned short* __restrict__ Vt) {
  int blk = blockIdx.x;                 // b*512 + h*32 + st
  int st = blk & 31, h = (blk >> 5) & 15, b = blk >> 9;
  int s0 = st * 64;
  int tid = threadIdx.x;
  int sl = tid >> 2, quad = tid & 3;
  int s = s0 + sl;
  int bh = b * NHEAD + h;

  float cs[8], sn[8];
#pragma unroll
  for (int j = 0; j < 8; ++j) {
    int pr = quad * 8 + j;
    float freq = 1.0f / (powf(10000.0f, (float)pr * (1.0f / 32.0f)) + 1.1920928955078125e-07f);
    float ang = (float)s * freq;
    sincosf(ang, &sn[j], &cs[j]);
  }
  const unsigned short* row = qkv + (size_t)(b * S_LEN + s) * 3072;
  // Q (pre-scaled by DIM_K^-0.5 = 1/32, exact in bf16)
  {
    float x1[8], x2[8];
    unpack8(*(const uint4*)&row[h * 64 + quad * 8], x1);
    unpack8(*(const uint4*)&row[h * 64 + 32 + quad * 8], x2);
    unsigned short o1[8], o2[8];
#pragma unroll
    for (int j = 0; j < 8; ++j) {
      o1[j] = f2bf((x1[j] * cs[j] - x2[j] * sn[j]) * 0.03125f);
      o2[j] = f2bf((x2[j] * cs[j] + x1[j] * sn[j]) * 0.03125f);
    }
    unsigned short* qp = Qh + ((size_t)bh * S_LEN + s) * 64 + quad * 8;
    *(uint4*)qp = pack8(o1);
    *(uint4*)(qp + 32) = pack8(o2);
  }
  // K (no scale)
  {
    float x1[8], x2[8];
    unpack8(*(const uint4*)&row[1024 + h * 64 + quad * 8], x1);
    unpack8(*(const uint4*)&row[1024 + h * 64 + 32 + quad * 8], x2);
    unsigned short o1[8], o2[8];
#pragma unroll
    for (int j = 0; j < 8; ++j) {
      o1[j] = f2bf(x1[j] * cs[j] - x2[j] * sn[j]);
      o2[j] = f2bf(x2[j] * cs[j] + x1[j] * sn[j]);
    }
    unsigned short* kp = Kh + ((size_t)bh * S_LEN + s) * 64 + quad * 8;
    *(uint4*)kp = pack8(o1);
    *(uint4*)(kp + 32) = pack8(o2);
  }
  // V: transpose 64x64 tile through LDS -> Vt[bh][d][s]
  __shared__ unsigned short Vl[64 * 72];
#pragma unroll
  for (int i = 0; i < 2; ++i) {
    int c = tid + i * 256;
    int r = c >> 3, c8 = (c & 7) * 8;
    *(uint4*)&Vl[r * 72 + c8] =
        *(const uint4*)&qkv[(size_t)(b * S_LEN + s0 + r) * 3072 + 2048 + h * 64 + c8];
  }
  __syncthreads();
  int d = tid >> 2, sc4 = tid & 3;
  unsigned o[8];
#pragma unroll
  for (int jj = 0; jj < 8; ++jj) {
    int sidx = sc4 * 16 + jj * 2;
    o[jj] = (unsigned)Vl[sidx * 72 + d] | ((unsigned)Vl[(sidx + 1) * 72 + d] << 16);
  }
  unsigned short* vp = Vt + ((size_t)bh * 64 + d) * S_LEN + s0 + sc4 * 16;
  *(uint4*)vp = make_uint4(o[0], o[1], o[2], o[3]);
  *(uint4*)(vp + 8) = make_uint4(o[4], o[5], o[6], o[7]);
}

// ---------------- causal flash attention, swapped-QK^T 32x32 structure ----------------
// 512 blocks x 256 thr. Wave w of block handles q-tile qt in {k,31-k,32+k,63-k} (balanced).
// Per wave: 32 q-rows, KV tiles of 32 read per-lane from L2 (no LDS staging, no barriers).
// S^T = mfma(K, Q): lane holds 16 scores for q=lane&31 -> in-register softmax; cross-half
// combines via __shfl_xor(.,32). O^T = mfma(V^T, P): rescale factor per-lane scalar.
// LDS only for the per-wave epilogue transpose.
__global__ __launch_bounds__(256) void k_attn2(const unsigned short* __restrict__ Qh,
                                               const unsigned short* __restrict__ Kh,
                                               const unsigned short* __restrict__ Vt,
                                               unsigned short* __restrict__ O) {
  __shared__ unsigned short Ol[4][32 * 72];
  int bid = blockIdx.x;
  int xcd = bid & 7, idx = bid >> 3;       // XCD swizzle: bh group pinned to one XCD's L2
  int bh = xcd * 4 + (idx >> 4);
  int kb = idx & 15;
  int tid = threadIdx.x, w = tid >> 6, lane = tid & 63;
  int qt = (w == 0) ? kb : (w == 1) ? (31 - kb) : (w == 2) ? (32 + kb) : (63 - kb);
  int q0 = qt * 32;
  int b = bh >> 4, h = bh & 15;
  int l31 = lane & 31, hi = lane >> 5;

  const unsigned short* Qg = Qh + ((size_t)bh * S_LEN + q0 + l31) * 64 + hi * 8;
  const unsigned short* Kg = Kh + ((size_t)bh * S_LEN + l31) * 64 + hi * 8;
  const unsigned short* Vg = Vt + ((size_t)bh * 64 + l31) * S_LEN + hi * 8;

  bf16x8 qf[4];
#pragma unroll
  for (int c = 0; c < 4; ++c) qf[c] = *(const bf16x8*)(Qg + c * 16);

  f32x16 acc0, acc1;
#pragma unroll
  for (int r = 0; r < 16; ++r) { acc0[r] = 0.f; acc1[r] = 0.f; }
  float m_run = -1e30f, l_run = 0.f;

  bf16x8 kf[4], vf[4], kn[4], vn[4];
#pragma unroll
  for (int c = 0; c < 4; ++c) kf[c] = *(const bf16x8*)(Kg + c * 16);
#pragma unroll
  for (int dh = 0; dh < 2; ++dh)
#pragma unroll
    for (int c = 0; c < 2; ++c)
      vf[dh * 2 + c] = *(const bf16x8*)(Vg + (size_t)dh * 32 * S_LEN + c * 16);

  for (int t = 0; t <= qt; ++t) {
    // prefetch next tile (clamped; redundant reload on last iter)
    int tn = (t < qt) ? t + 1 : t;
    {
      const unsigned short* kp = Kg + (size_t)tn * 32 * 64;
#pragma unroll
      for (int c = 0; c < 4; ++c) kn[c] = *(const bf16x8*)(kp + c * 16);
      const unsigned short* vp = Vg + tn * 32;
#pragma unroll
      for (int dh = 0; dh < 2; ++dh)
#pragma unroll
        for (int c = 0; c < 2; ++c)
          vn[dh * 2 + c] = *(const bf16x8*)(vp + (size_t)dh * 32 * S_LEN + c * 16);
    }
    // S^T[k][q] : 4 MFMA over d-chunks
    f32x16 s;
#pragma unroll
    for (int r = 0; r < 16; ++r) s[r] = 0.f;
#pragma unroll
    for (int c = 0; c < 4; ++c)
      s = __builtin_amdgcn_mfma_f32_32x32x16_bf16(kf[c], qf[c], s, 0, 0, 0);
    if (t == qt) {  // diagonal: mask kv_row > q_col
#pragma unroll
      for (int r = 0; r < 16; ++r) {
        int krow = (r & 3) + 8 * (r >> 2) + 4 * hi;
        if (krow > l31) s[r] = -1e30f;
      }
    }
    // row max (q = l31; combine the two lane-halves via shfl_xor 32)
    float pmax;
    {
      float m0 = fmaxf(s[0], s[1]),   m1 = fmaxf(s[2], s[3]);
      float m2 = fmaxf(s[4], s[5]),   m3 = fmaxf(s[6], s[7]);
      float m4 = fmaxf(s[8], s[9]),   m5 = fmaxf(s[10], s[11]);
      float m6 = fmaxf(s[12], s[13]), m7 = fmaxf(s[14], s[15]);
      m0 = fmaxf(m0, m1); m2 = fmaxf(m2, m3); m4 = fmaxf(m4, m5); m6 = fmaxf(m6, m7);
      pmax = fmaxf(fmaxf(m0, m2), fmaxf(m4, m6));
      pmax = fmaxf(pmax, __shfl_xor(pmax, 32));
    }
    // deferred-max online softmax (T13, THR=8)
    if (__any(pmax > m_run + 8.0f)) {
      float mnew = fmaxf(m_run, pmax);
      float fac = __expf(m_run - mnew);
      l_run *= fac;
#pragma unroll
      for (int r = 0; r < 16; ++r) { acc0[r] *= fac; acc1[r] *= fac; }
      m_run = mnew;
    }
    f32x16 p;
#pragma unroll
    for (int r = 0; r < 16; ++r) p[r] = __expf(s[r] - m_run);
    {
      float s0 = (p[0] + p[1]) + (p[2] + p[3]);
      float s1 = (p[4] + p[5]) + (p[6] + p[7]);
      float s2 = (p[8] + p[9]) + (p[10] + p[11]);
      float s3 = (p[12] + p[13]) + (p[14] + p[15]);
      float rs = (s0 + s1) + (s2 + s3);
      l_run += rs + __shfl_xor(rs, 32);
    }
    // P -> bf16 B-fragments: cvt_pk pairs, cross-half exchange via shfl_xor(32)
    // lane (q,hi) target element j of slice c must hold P[q][16c + 8*hi + j].
    bf16x8 pf[2];
#pragma unroll
    for (int c = 0; c < 2; ++c) {
      const int o = c * 8;
      unsigned x0, x1, y0, y1;
      asm("v_cvt_pk_bf16_f32 %0, %1, %2" : "=v"(x0) : "v"(p[o + 0]), "v"(p[o + 1]));
      asm("v_cvt_pk_bf16_f32 %0, %1, %2" : "=v"(x1) : "v"(p[o + 2]), "v"(p[o + 3]));
      asm("v_cvt_pk_bf16_f32 %0, %1, %2" : "=v"(y0) : "v"(p[o + 4]), "v"(p[o + 5]));
      asm("v_cvt_pk_bf16_f32 %0, %1, %2" : "=v"(y1) : "v"(p[o + 6]), "v"(p[o + 7]));
      unsigned sx0 = (unsigned)__shfl_xor((int)x0, 32);
      unsigned sx1 = (unsigned)__shfl_xor((int)x1, 32);
      unsigned sy0 = (unsigned)__shfl_xor((int)y0, 32);
      unsigned sy1 = (unsigned)__shfl_xor((int)y1, 32);
      unsigned w0 = hi ? sy0 : x0;
      unsigned w1 = hi ? sy1 : x1;
      unsigned w2 = hi ? y0 : sx0;
      unsigned w3 = hi ? y1 : sx1;
      union { uint4 u; bf16x8 v; } cv;
      cv.u = make_uint4(w0, w1, w2, w3);
      pf[c] = cv.v;
    }
    // O^T += V^T * P
#pragma unroll
    for (int c = 0; c < 2; ++c) {
      acc0 = __builtin_amdgcn_mfma_f32_32x32x16_bf16(vf[c], pf[c], acc0, 0, 0, 0);
      acc1 = __builtin_amdgcn_mfma_f32_32x32x16_bf16(vf[2 + c], pf[c], acc1, 0, 0, 0);
    }
#pragma unroll
    for (int c = 0; c < 4; ++c) { kf[c] = kn[c]; vf[c] = vn[c]; }
  }

  // epilogue: O^T regs -> per-wave LDS [32 q][64 dv] -> coalesced global store
  float inv = 1.0f / l_run;
  unsigned short* ol = &Ol[w][0];
#pragma unroll
  for (int dh = 0; dh < 2; ++dh) {
#pragma unroll
    for (int r = 0; r < 16; r += 2) {
      int dv = dh * 32 + (r & 3) + 8 * (r >> 2) + 4 * hi;
      float lo = (dh ? acc1[r] : acc0[r]) * inv;
      float hi_ = (dh ? acc1[r + 1] : acc0[r + 1]) * inv;
      unsigned u;
      asm("v_cvt_pk_bf16_f32 %0, %1, %2" : "=v"(u) : "v"(lo), "v"(hi_));
      *(unsigned*)&ol[l31 * 72 + dv] = u;
    }
  }
  asm volatile("s_waitcnt lgkmcnt(0)" ::: "memory");
  {
    int q = lane >> 1, half = lane & 1;
    unsigned short* op = O + ((size_t)(b * S_LEN + q0 + q)) * 1024 + h * 64 + half * 32;
#pragma unroll
    for (int j = 0; j < 4; ++j)
      *(uint4*)(op + j * 8) = *(const uint4*)&ol[q * 72 + half * 32 + j * 8];
  }
}

extern "C" void kernel_launch(void* const* d_in, const int* in_sizes, int n_in,
                              void* d_out, int out_size, void* d_ws, size_t ws_size,
                              hipStream_t stream) {
  const float* x = (const float*)d_in[0];
  const float* Wqkv = (const float*)d_in[1];
  const float* Wout = (const float*)d_in[2];
  float* out = (float*)d_out;
  char* ws = (char*)d_ws;
  // layout (bytes): xb/O 0..8M | WqkvT 8..14M | WoutT 14..16M | qkv 16..40M |
  //                 Qh 40..48M | Kh 48..56M | Vt 56..64M
  unsigned short* xb = (unsigned short*)(ws);
  unsigned short* WqkvT = (unsigned short*)(ws + ((size_t)8 << 20));
  unsigned short* WoutT = (unsigned short*)(ws + ((size_t)14 << 20));
  unsigned short* qkv = (unsigned short*)(ws + ((size_t)16 << 20));
  unsigned short* Qh = (unsigned short*)(ws + ((size_t)40 << 20));
  unsigned short* Kh = (unsigned short*)(ws + ((size_t)48 << 20));
  unsigned short* Vt = (unsigned short*)(ws + ((size_t)56 << 20));

  k_cvt<<<2048, 256, 0, stream>>>(x, xb, 4096 * 1024 / 8);
  k_transpose_cvt<<<dim3(16, 48), 256, 0, stream>>>(Wqkv, WqkvT, 1024, 3072);
  k_transpose_cvt<<<dim3(16, 16), 256, 0, stream>>>(Wout, WoutT, 1024, 1024);
  k_gemm_bt<unsigned short><<<dim3(32, 24), 256, 0, stream>>>(xb, WqkvT, qkv, 4096, 3072, 1024);
  k_rope_split<<<1024, 256, 0, stream>>>(qkv, Qh, Kh, Vt);
  k_attn2<<<512, 256, 0, stream>>>(Qh, Kh, Vt, xb /* reuse as O [B][S][1024] */);
  k_gemm_bt<float><<<dim3(32, 8), 256, 0, stream>>>(xb, WoutT, out, 4096, 1024, 1024);
}

// Round 4
// 158.728 us; speedup vs baseline: 1.3845x; 1.0403x over previous
//
#include <hip/hip_runtime.h>

#define S_LEN 2048
#define NHEAD 16

using f32x4  = __attribute__((ext_vector_type(4))) float;
using f32x16 = __attribute__((ext_vector_type(16))) float;
using bf16x8 = __attribute__((ext_vector_type(8))) __bf16;

__device__ __forceinline__ unsigned short f2bf(float f) {
  union { float f; unsigned u; } v; v.f = f;
  unsigned r = v.u + 0x7FFFu + ((v.u >> 16) & 1u);
  return (unsigned short)(r >> 16);
}
__device__ __forceinline__ float bf2f(unsigned short h) {
  union { unsigned u; float f; } v; v.u = ((unsigned)h) << 16; return v.f;
}
__device__ __forceinline__ void unpack8(uint4 u, float x[8]) {
  x[0]=bf2f((unsigned short)(u.x&0xffff)); x[1]=bf2f((unsigned short)(u.x>>16));
  x[2]=bf2f((unsigned short)(u.y&0xffff)); x[3]=bf2f((unsigned short)(u.y>>16));
  x[4]=bf2f((unsigned short)(u.z&0xffff)); x[5]=bf2f((unsigned short)(u.z>>16));
  x[6]=bf2f((unsigned short)(u.w&0xffff)); x[7]=bf2f((unsigned short)(u.w>>16));
}
__device__ __forceinline__ uint4 pack8(const unsigned short o[8]) {
  uint4 u;
  u.x = (unsigned)o[0] | ((unsigned)o[1]<<16);
  u.y = (unsigned)o[2] | ((unsigned)o[3]<<16);
  u.z = (unsigned)o[4] | ((unsigned)o[5]<<16);
  u.w = (unsigned)o[6] | ((unsigned)o[7]<<16);
  return u;
}
__device__ __forceinline__ void gload16(const void* g, void* l) {
  __builtin_amdgcn_global_load_lds(
      (const __attribute__((address_space(1))) unsigned int*)g,
      (__attribute__((address_space(3))) unsigned int*)l, 16, 0, 0);
}
__device__ __forceinline__ void store_c(float* C, size_t off, float v) { C[off] = v; }
__device__ __forceinline__ void store_c(unsigned short* C, size_t off, float v) { C[off] = f2bf(v); }

// ---------------- fp32 -> bf16 convert (vectorized, 8 elems/thread) ----------------
__global__ __launch_bounds__(256) void k_cvt(const float* __restrict__ in,
                                             unsigned short* __restrict__ out, int n8) {
  int i = blockIdx.x * 256 + threadIdx.x;
  if (i >= n8) return;
  const float4* p = (const float4*)in + 2 * (size_t)i;
  float4 a = p[0], b = p[1];
  unsigned short o[8] = { f2bf(a.x), f2bf(a.y), f2bf(a.z), f2bf(a.w),
                          f2bf(b.x), f2bf(b.y), f2bf(b.z), f2bf(b.w) };
  ((uint4*)out)[i] = pack8(o);
}

// ---------------- fp32 [R][C] -> bf16 transposed [C][R] ----------------
__global__ __launch_bounds__(256) void k_transpose_cvt(const float* __restrict__ in,
                                                       unsigned short* __restrict__ out,
                                                       int R, int C) {
  __shared__ float T[64][65];
  int r0 = blockIdx.x * 64, c0 = blockIdx.y * 64;
  int tid = threadIdx.x;
#pragma unroll
  for (int i = 0; i < 16; ++i) {
    int idx = tid + i * 256;
    int r = idx >> 6, c = idx & 63;
    T[r][c] = in[(size_t)(r0 + r) * C + c0 + c];
  }
  __syncthreads();
#pragma unroll
  for (int i = 0; i < 8; ++i) {
    int idx = tid + i * 256;
    int co = idx >> 5, rp = (idx & 31) * 2;
    unsigned v = (unsigned)f2bf(T[rp][co]) | ((unsigned)f2bf(T[rp + 1][co]) << 16);
    *(unsigned*)&out[(size_t)(c0 + co) * R + r0 + rp] = v;
  }
}

// ---------------- bf16 GEMM: C[M][N] = A[M][K] * Bt[N][K]^T  (m97-style 128x128x32) --
template <typename OUT_T>
__global__ __launch_bounds__(256) void k_gemm_bt(const unsigned short* __restrict__ A,
                                                 const unsigned short* __restrict__ Bt,
                                                 OUT_T* __restrict__ C,
                                                 int M, int N, int K) {
  __shared__ unsigned short As[128 * 32];
  __shared__ unsigned short Bs[128 * 32];
  int m0 = blockIdx.x * 128, n0 = blockIdx.y * 128;
  int tid = threadIdx.x;
  int lane = tid & 63, w = tid >> 6;
  int wr = w >> 1, wc = w & 1;
  int li = lane & 15, g = lane >> 4;

  const unsigned short* a_s0 = A + (size_t)(m0 + (tid >> 2)) * K + (tid & 3) * 8;
  const unsigned short* a_s1 = A + (size_t)(m0 + 64 + (tid >> 2)) * K + (tid & 3) * 8;
  const unsigned short* b_s0 = Bt + (size_t)(n0 + (tid >> 2)) * K + (tid & 3) * 8;
  const unsigned short* b_s1 = Bt + (size_t)(n0 + 64 + (tid >> 2)) * K + (tid & 3) * 8;
  unsigned short* As_d0 = &As[(w * 64) * 8];
  unsigned short* As_d1 = &As[(256 + w * 64) * 8];
  unsigned short* Bs_d0 = &Bs[(w * 64) * 8];
  unsigned short* Bs_d1 = &Bs[(256 + w * 64) * 8];

  f32x4 acc[4][4];
#pragma unroll
  for (int i = 0; i < 4; ++i)
#pragma unroll
    for (int j = 0; j < 4; ++j) acc[i][j] = (f32x4){0.f, 0.f, 0.f, 0.f};

  int nk = K >> 5;
  for (int kt = 0; kt < nk; ++kt) {
    int k0 = kt << 5;
    gload16(a_s0 + k0, As_d0);
    gload16(a_s1 + k0, As_d1);
    gload16(b_s0 + k0, Bs_d0);
    gload16(b_s1 + k0, Bs_d1);
    __syncthreads();
    bf16x8 af[4], bfr[4];
#pragma unroll
    for (int i = 0; i < 4; ++i)
      af[i] = *(const bf16x8*)&As[(wr * 64 + i * 16 + li) * 32 + g * 8];
#pragma unroll
    for (int j = 0; j < 4; ++j)
      bfr[j] = *(const bf16x8*)&Bs[(wc * 64 + j * 16 + li) * 32 + g * 8];
#pragma unroll
    for (int i = 0; i < 4; ++i)
#pragma unroll
      for (int j = 0; j < 4; ++j)
        acc[i][j] = __builtin_amdgcn_mfma_f32_16x16x32_bf16(af[i], bfr[j], acc[i][j], 0, 0, 0);
    __syncthreads();
  }
#pragma unroll
  for (int i = 0; i < 4; ++i) {
    int row = m0 + wr * 64 + i * 16 + g * 4;
#pragma unroll
    for (int j = 0; j < 4; ++j) {
      int col = n0 + wc * 64 + j * 16 + li;
#pragma unroll
      for (int r = 0; r < 4; ++r) store_c(C, (size_t)(row + r) * N + col, acc[i][j][r]);
    }
  }
}

// ---------------- rope + head split:  qkv[B*S][3072] -> Qh,Kh [BH][S][64], Vt [BH][64][S]
__global__ __launch_bounds__(256) void k_rope_split(const unsigned short* __restrict__ qkv,
                                                    unsigned short* __restrict__ Qh,
                                                    unsigned short* __restrict__ Kh,
                                                    unsigned short* __restrict__ Vt) {
  int blk = blockIdx.x;                 // b*512 + h*32 + st
  int st = blk & 31, h = (blk >> 5) & 15, b = blk >> 9;
  int s0 = st * 64;
  int tid = threadIdx.x;
  int sl = tid >> 2, quad = tid & 3;
  int s = s0 + sl;
  int bh = b * NHEAD + h;

  float cs[8], sn[8];
#pragma unroll
  for (int j = 0; j < 8; ++j) {
    int pr = quad * 8 + j;
    float freq = 1.0f / (powf(10000.0f, (float)pr * (1.0f / 32.0f)) + 1.1920928955078125e-07f);
    float ang = (float)s * freq;
    sincosf(ang, &sn[j], &cs[j]);
  }
  const unsigned short* row = qkv + (size_t)(b * S_LEN + s) * 3072;
  // Q (pre-scaled by DIM_K^-0.5 = 1/32, exact in bf16)
  {
    float x1[8], x2[8];
    unpack8(*(const uint4*)&row[h * 64 + quad * 8], x1);
    unpack8(*(const uint4*)&row[h * 64 + 32 + quad * 8], x2);
    unsigned short o1[8], o2[8];
#pragma unroll
    for (int j = 0; j < 8; ++j) {
      o1[j] = f2bf((x1[j] * cs[j] - x2[j] * sn[j]) * 0.03125f);
      o2[j] = f2bf((x2[j] * cs[j] + x1[j] * sn[j]) * 0.03125f);
    }
    unsigned short* qp = Qh + ((size_t)bh * S_LEN + s) * 64 + quad * 8;
    *(uint4*)qp = pack8(o1);
    *(uint4*)(qp + 32) = pack8(o2);
  }
  // K (no scale)
  {
    float x1[8], x2[8];
    unpack8(*(const uint4*)&row[1024 + h * 64 + quad * 8], x1);
    unpack8(*(const uint4*)&row[1024 + h * 64 + 32 + quad * 8], x2);
    unsigned short o1[8], o2[8];
#pragma unroll
    for (int j = 0; j < 8; ++j) {
      o1[j] = f2bf(x1[j] * cs[j] - x2[j] * sn[j]);
      o2[j] = f2bf(x2[j] * cs[j] + x1[j] * sn[j]);
    }
    unsigned short* kp = Kh + ((size_t)bh * S_LEN + s) * 64 + quad * 8;
    *(uint4*)kp = pack8(o1);
    *(uint4*)(kp + 32) = pack8(o2);
  }
  // V: transpose 64x64 tile through LDS -> Vt[bh][d][s]
  __shared__ unsigned short Vl[64 * 72];
#pragma unroll
  for (int i = 0; i < 2; ++i) {
    int c = tid + i * 256;
    int r = c >> 3, c8 = (c & 7) * 8;
    *(uint4*)&Vl[r * 72 + c8] =
        *(const uint4*)&qkv[(size_t)(b * S_LEN + s0 + r) * 3072 + 2048 + h * 64 + c8];
  }
  __syncthreads();
  int d = tid >> 2, sc4 = tid & 3;
  unsigned o[8];
#pragma unroll
  for (int jj = 0; jj < 8; ++jj) {
    int sidx = sc4 * 16 + jj * 2;
    o[jj] = (unsigned)Vl[sidx * 72 + d] | ((unsigned)Vl[(sidx + 1) * 72 + d] << 16);
  }
  unsigned short* vp = Vt + ((size_t)bh * 64 + d) * S_LEN + s0 + sc4 * 16;
  *(uint4*)vp = make_uint4(o[0], o[1], o[2], o[3]);
  *(uint4*)(vp + 8) = make_uint4(o[4], o[5], o[6], o[7]);
}

// ---------------- causal flash attention, swapped-QK^T 32x32, zero per-iter DS ops ----
// 512 blocks x 4 waves. Block bid: xcd=bid&7, i=bid>>3, a=i&31, hp=i>>5.
// Wave w: bh = xcd*4 + hp*2 + (w&1), qt = (w<2) ? a : 63-a  (span-balanced, XCD-local KV).
// K rows are loaded bit2<->bit3-permuted so S^T's C/D rows land in PV B-fragment order:
// lane (q=lane&31, hi) element r holds kv = (r&7) + 16*(r>>3) + 8*hi. P fragments are then
// pure cvt_pk of consecutive regs -> no cross-lane ops in the loop. pmax shfl only inside
// the rare rescale branch; l combined once in the epilogue.
__global__ __launch_bounds__(256) void k_attn2(const unsigned short* __restrict__ Qh,
                                               const unsigned short* __restrict__ Kh,
                                               const unsigned short* __restrict__ Vt,
                                               unsigned short* __restrict__ O) {
  __shared__ unsigned short Ol[4][32 * 72];
  int bid = blockIdx.x;
  int xcd = bid & 7, i = bid >> 3;
  int a = i & 31, hp = i >> 5;
  int tid = threadIdx.x, w = tid >> 6, lane = tid & 63;
  int bh = xcd * 4 + hp * 2 + (w & 1);
  int qt = (w < 2) ? a : 63 - a;
  int q0 = qt * 32;
  int b = bh >> 4, h = bh & 15;
  int l31 = lane & 31, hi = lane >> 5;
  // K-row permutation: swap bits 2 and 3 of l31
  int kperm = (l31 & 0x13) | ((l31 & 4) << 1) | ((l31 & 8) >> 1);

  const unsigned short* Qg = Qh + ((size_t)bh * S_LEN + q0 + l31) * 64 + hi * 8;
  const unsigned short* Kg = Kh + ((size_t)bh * S_LEN + kperm) * 64 + hi * 8;
  const unsigned short* Vg = Vt + ((size_t)bh * 64 + l31) * S_LEN + hi * 8;

  bf16x8 qf[4];
#pragma unroll
  for (int c = 0; c < 4; ++c) qf[c] = *(const bf16x8*)(Qg + c * 16);

  f32x16 acc0, acc1;
#pragma unroll
  for (int r = 0; r < 16; ++r) { acc0[r] = 0.f; acc1[r] = 0.f; }
  float m_run = -1e30f, l_run = 0.f;

  bf16x8 kf[4], vf[4], kn[4], vn[4];
#pragma unroll
  for (int c = 0; c < 4; ++c) kf[c] = *(const bf16x8*)(Kg + c * 16);
#pragma unroll
  for (int dh = 0; dh < 2; ++dh)
#pragma unroll
    for (int c = 0; c < 2; ++c)
      vf[dh * 2 + c] = *(const bf16x8*)(Vg + (size_t)dh * 32 * S_LEN + c * 16);

  for (int t = 0; t <= qt; ++t) {
    // prefetch next tile (clamped; redundant reload on last iter)
    int tn = (t < qt) ? t + 1 : t;
    {
      const unsigned short* kp = Kg + (size_t)tn * 32 * 64;
#pragma unroll
      for (int c = 0; c < 4; ++c) kn[c] = *(const bf16x8*)(kp + c * 16);
      const unsigned short* vp = Vg + tn * 32;
#pragma unroll
      for (int dh = 0; dh < 2; ++dh)
#pragma unroll
        for (int c = 0; c < 2; ++c)
          vn[dh * 2 + c] = *(const bf16x8*)(vp + (size_t)dh * 32 * S_LEN + c * 16);
    }
    // S^T[kv][q] : 4 chained MFMA over d-chunks
    f32x16 s;
#pragma unroll
    for (int r = 0; r < 16; ++r) s[r] = 0.f;
    __builtin_amdgcn_s_setprio(1);
#pragma unroll
    for (int c = 0; c < 4; ++c)
      s = __builtin_amdgcn_mfma_f32_32x32x16_bf16(kf[c], qf[c], s, 0, 0, 0);
    __builtin_amdgcn_s_setprio(0);
    if (t == qt) {  // diagonal: mask kv > q  (kv per permuted layout)
#pragma unroll
      for (int r = 0; r < 16; ++r) {
        int kv = (r & 7) + 16 * (r >> 3) + 8 * hi;
        if (kv > l31) s[r] = -1e30f;
      }
    }
    // local (16-score) max; cross-half combine deferred to the rare rescale branch
    float pmax;
    {
      float m0 = fmaxf(s[0], s[1]),   m1 = fmaxf(s[2], s[3]);
      float m2 = fmaxf(s[4], s[5]),   m3 = fmaxf(s[6], s[7]);
      float m4 = fmaxf(s[8], s[9]),   m5 = fmaxf(s[10], s[11]);
      float m6 = fmaxf(s[12], s[13]), m7 = fmaxf(s[14], s[15]);
      m0 = fmaxf(m0, m1); m2 = fmaxf(m2, m3); m4 = fmaxf(m4, m5); m6 = fmaxf(m6, m7);
      pmax = fmaxf(fmaxf(m0, m2), fmaxf(m4, m6));
    }
    if (__any(pmax > m_run + 8.0f)) {   // deferred-max (T13); fires ~once per wave
      float pfull = fmaxf(pmax, __shfl_xor(pmax, 32));
      float mnew = fmaxf(m_run, pfull);
      float fac = __expf(m_run - mnew);
      l_run *= fac;
#pragma unroll
      for (int r = 0; r < 16; ++r) { acc0[r] *= fac; acc1[r] *= fac; }
      m_run = mnew;
    }
    f32x16 p;
#pragma unroll
    for (int r = 0; r < 16; ++r) p[r] = __expf(s[r] - m_run);
    {
      float s0 = (p[0] + p[1]) + (p[2] + p[3]);
      float s1 = (p[4] + p[5]) + (p[6] + p[7]);
      float s2 = (p[8] + p[9]) + (p[10] + p[11]);
      float s3 = (p[12] + p[13]) + (p[14] + p[15]);
      l_run += (s0 + s1) + (s2 + s3);   // per-half partial; combined in epilogue
    }
    // P -> bf16 B-fragments: pure cvt_pk, consecutive regs (kv order matches B layout)
    bf16x8 pf[2];
#pragma unroll
    for (int c = 0; c < 2; ++c) {
      const int o = c * 8;
      unsigned w0, w1, w2, w3;
      asm("v_cvt_pk_bf16_f32 %0, %1, %2" : "=v"(w0) : "v"(p[o + 0]), "v"(p[o + 1]));
      asm("v_cvt_pk_bf16_f32 %0, %1, %2" : "=v"(w1) : "v"(p[o + 2]), "v"(p[o + 3]));
      asm("v_cvt_pk_bf16_f32 %0, %1, %2" : "=v"(w2) : "v"(p[o + 4]), "v"(p[o + 5]));
      asm("v_cvt_pk_bf16_f32 %0, %1, %2" : "=v"(w3) : "v"(p[o + 6]), "v"(p[o + 7]));
      union { uint4 u; bf16x8 v; } cv;
      cv.u = make_uint4(w0, w1, w2, w3);
      pf[c] = cv.v;
    }
    // O^T += V^T * P
    __builtin_amdgcn_s_setprio(1);
#pragma unroll
    for (int c = 0; c < 2; ++c) {
      acc0 = __builtin_amdgcn_mfma_f32_32x32x16_bf16(vf[c], pf[c], acc0, 0, 0, 0);
      acc1 = __builtin_amdgcn_mfma_f32_32x32x16_bf16(vf[2 + c], pf[c], acc1, 0, 0, 0);
    }
    __builtin_amdgcn_s_setprio(0);
#pragma unroll
    for (int c = 0; c < 4; ++c) { kf[c] = kn[c]; vf[c] = vn[c]; }
  }

  // epilogue: combine l halves, then O^T regs -> per-wave LDS -> coalesced store
  float l_tot = l_run + __shfl_xor(l_run, 32);
  float inv = 1.0f / l_tot;
  unsigned short* ol = &Ol[w][0];
#pragma unroll
  for (int dh = 0; dh < 2; ++dh) {
#pragma unroll
    for (int r = 0; r < 16; r += 2) {
      int dv = dh * 32 + (r & 3) + 8 * (r >> 2) + 4 * hi;
      float lo = (dh ? acc1[r] : acc0[r]) * inv;
      float hi_ = (dh ? acc1[r + 1] : acc0[r + 1]) * inv;
      unsigned u;
      asm("v_cvt_pk_bf16_f32 %0, %1, %2" : "=v"(u) : "v"(lo), "v"(hi_));
      *(unsigned*)&ol[l31 * 72 + dv] = u;
    }
  }
  asm volatile("s_waitcnt lgkmcnt(0)" ::: "memory");
  {
    int q = lane >> 1, half = lane & 1;
    unsigned short* op = O + ((size_t)(b * S_LEN + q0 + q)) * 1024 + h * 64 + half * 32;
#pragma unroll
    for (int j = 0; j < 4; ++j)
      *(uint4*)(op + j * 8) = *(const uint4*)&ol[q * 72 + half * 32 + j * 8];
  }
}

extern "C" void kernel_launch(void* const* d_in, const int* in_sizes, int n_in,
                              void* d_out, int out_size, void* d_ws, size_t ws_size,
                              hipStream_t stream) {
  const float* x = (const float*)d_in[0];
  const float* Wqkv = (const float*)d_in[1];
  const float* Wout = (const float*)d_in[2];
  float* out = (float*)d_out;
  char* ws = (char*)d_ws;
  // layout (bytes): xb/O 0..8M | WqkvT 8..14M | WoutT 14..16M | qkv 16..40M |
  //                 Qh 40..48M | Kh 48..56M | Vt 56..64M
  unsigned short* xb = (unsigned short*)(ws);
  unsigned short* WqkvT = (unsigned short*)(ws + ((size_t)8 << 20));
  unsigned short* WoutT = (unsigned short*)(ws + ((size_t)14 << 20));
  unsigned short* qkv = (unsigned short*)(ws + ((size_t)16 << 20));
  unsigned short* Qh = (unsigned short*)(ws + ((size_t)40 << 20));
  unsigned short* Kh = (unsigned short*)(ws + ((size_t)48 << 20));
  unsigned short* Vt = (unsigned short*)(ws + ((size_t)56 << 20));

  k_cvt<<<2048, 256, 0, stream>>>(x, xb, 4096 * 1024 / 8);
  k_transpose_cvt<<<dim3(16, 48), 256, 0, stream>>>(Wqkv, WqkvT, 1024, 3072);
  k_transpose_cvt<<<dim3(16, 16), 256, 0, stream>>>(Wout, WoutT, 1024, 1024);
  k_gemm_bt<unsigned short><<<dim3(32, 24), 256, 0, stream>>>(xb, WqkvT, qkv, 4096, 3072, 1024);
  k_rope_split<<<1024, 256, 0, stream>>>(qkv, Qh, Kh, Vt);
  k_attn2<<<512, 256, 0, stream>>>(Qh, Kh, Vt, xb /* reuse as O [B][S][1024] */);
  k_gemm_bt<float><<<dim3(32, 8), 256, 0, stream>>>(xb, WoutT, out, 4096, 1024, 1024);
}